// Round 1
// baseline (384.953 us; speedup 1.0000x reference)
//
#include <hip/hip_runtime.h>

#define TPB 256

// ---------------------------------------------------------------------------
// Edge-index dtype detection: if edge_index is int64 (little-endian, values in
// [0,50000)), every odd 32-bit word is a zero high-word. If int32, odd words
// are real node ids (P[all 64 samples == 0] ~ (1/50000)^64 ~ 0).
// ---------------------------------------------------------------------------
__global__ void detect_idx(const unsigned int* w, int* flag) {
    __shared__ unsigned int s[64];
    int t = threadIdx.x;
    s[t] = w[2 * t + 1];
    __syncthreads();
    if (t == 0) {
        unsigned int acc = 0;
        for (int i = 0; i < 64; ++i) acc |= s[i];
        *flag = (acc == 0u) ? 1 : 0;   // 1 => int64, 0 => int32
    }
}

__device__ __forceinline__ int ld_idx(const void* p, long long i, int is64) {
    return is64 ? (int)((const long long*)p)[i] : ((const int*)p)[i];
}

// deg[v] = 1 (self loop) + in-degree
__global__ void deg_init(int* deg, int n) {
    int i = blockIdx.x * TPB + threadIdx.x;
    if (i < n) deg[i] = 1;
}

__global__ void deg_count(const void* ei, long long E, const int* flag, int* deg) {
    long long e = (long long)blockIdx.x * TPB + threadIdx.x;
    if (e < E) {
        int is64 = *flag;
        int d = ld_idx(ei, E + e, is64);
        atomicAdd(&deg[d], 1);
    }
}

__global__ void make_dis(const int* deg, float* dis, int n) {
    int i = blockIdx.x * TPB + threadIdx.x;
    if (i < n) dis[i] = rsqrtf((float)deg[i]);   // deg >= 1 always (self loop)
}

// Exclusive scan of (deg[i]-1) = CSR row offsets for the real edges.
__global__ void scan_blocks(const int* deg, int* offsets, int* bsums, int n) {
    __shared__ int s[TPB];
    int tid = threadIdx.x;
    int i = blockIdx.x * TPB + tid;
    int v = (i < n) ? (deg[i] - 1) : 0;
    s[tid] = v;
    __syncthreads();
    for (int off = 1; off < TPB; off <<= 1) {
        int t = 0;
        if (tid >= off) t = s[tid - off];
        __syncthreads();
        s[tid] += t;
        __syncthreads();
    }
    if (i < n) offsets[i] = s[tid] - v;          // exclusive within block
    if (tid == TPB - 1) bsums[blockIdx.x] = s[tid];
}

__global__ void scan_bsums(int* bsums, int nb) {
    if (threadIdx.x == 0 && blockIdx.x == 0) {
        int acc = 0;
        for (int b = 0; b < nb; ++b) { int v = bsums[b]; bsums[b] = acc; acc += v; }
    }
}

__global__ void add_bsums(int* offsets, const int* bsums, int* cursor, int n) {
    int i = blockIdx.x * TPB + threadIdx.x;
    if (i < n) {
        int o = offsets[i] + bsums[blockIdx.x];
        offsets[i] = o;
        cursor[i] = o;
    }
}

__global__ void fill_csr(const void* ei, long long E, const int* flag,
                         int* cursor, int* csr) {
    long long e = (long long)blockIdx.x * TPB + threadIdx.x;
    if (e < E) {
        int is64 = *flag;
        int s = ld_idx(ei, e, is64);
        int d = ld_idx(ei, E + e, is64);
        int pos = atomicAdd(&cursor[d], 1);
        csr[pos] = s;
    }
}

// ---------------------------------------------------------------------------
// y[v,f] = dis[v] * sum_k x[v,k] * W[k,f]    (d = 64)
// Block = 256 threads = 4 waves = 4 nodes; W (16 KB) in LDS; x-row read from
// LDS is wave-uniform (broadcast, conflict-free); W read is 2 lanes/bank (free).
// ---------------------------------------------------------------------------
__global__ __launch_bounds__(TPB) void gemm_scale(const float* __restrict__ x,
                                                  const float* __restrict__ W,
                                                  const float* __restrict__ dis,
                                                  float* __restrict__ y, int n) {
    __shared__ float Ws[64 * 64];
    __shared__ float xs[4 * 64];
    int t = threadIdx.x;
    const float4* W4 = (const float4*)W;
    float4* Ws4 = (float4*)Ws;
    #pragma unroll
    for (int i = 0; i < 4; ++i) Ws4[t + i * TPB] = W4[t + i * TPB];

    int vi = t >> 6, f = t & 63;
    int v = blockIdx.x * 4 + vi;
    xs[t] = (v < n) ? x[(long long)v * 64 + f] : 0.0f;
    __syncthreads();

    float acc = 0.0f;
    #pragma unroll
    for (int k = 0; k < 64; ++k) acc = fmaf(xs[vi * 64 + k], Ws[k * 64 + f], acc);

    if (v < n) y[(long long)v * 64 + f] = acc * dis[v];
}

// ---------------------------------------------------------------------------
// out[v] = relu(dis[v] * (y[v] + sum_{in-edges} y[src]) + b)
// 16 threads per node, float4 per thread (64 features). csr read is
// quarter-wave-uniform (broadcast).
// ---------------------------------------------------------------------------
__global__ __launch_bounds__(TPB) void gather_relu(const float* __restrict__ y,
                                                   const int* __restrict__ csr,
                                                   const int* __restrict__ offsets,
                                                   const int* __restrict__ deg,
                                                   const float* __restrict__ dis,
                                                   const float* __restrict__ b,
                                                   float* __restrict__ xout, int n) {
    int gid = blockIdx.x * TPB + threadIdx.x;
    int node = gid >> 4;
    int c = gid & 15;
    if (node >= n) return;

    const float4* y4 = (const float4*)y;
    float4 acc = y4[node * 16 + c];              // self-loop term
    int start = offsets[node];
    int cnt = deg[node] - 1;
    for (int j = 0; j < cnt; ++j) {
        int s = csr[start + j];
        float4 m = y4[s * 16 + c];
        acc.x += m.x; acc.y += m.y; acc.z += m.z; acc.w += m.w;
    }
    float dv = dis[node];
    float4 bb = ((const float4*)b)[c];
    float4 o;
    o.x = fmaxf(fmaf(dv, acc.x, bb.x), 0.0f);
    o.y = fmaxf(fmaf(dv, acc.y, bb.y), 0.0f);
    o.z = fmaxf(fmaf(dv, acc.z, bb.z), 0.0f);
    o.w = fmaxf(fmaf(dv, acc.w, bb.w), 0.0f);
    ((float4*)xout)[node * 16 + c] = o;
}

// out[v,o] = sum_k x[v,k] * Wl[k,o] + bl[o]   (64 -> 8)
__global__ __launch_bounds__(TPB) void final_lin(const float* __restrict__ x,
                                                 const float* __restrict__ Wl,
                                                 const float* __restrict__ bl,
                                                 float* __restrict__ out, int n) {
    __shared__ float Ws[64 * 8];
    __shared__ float bs[8];
    int t = threadIdx.x;
    for (int i = t; i < 512; i += TPB) Ws[i] = Wl[i];
    if (t < 8) bs[t] = bl[t];
    __syncthreads();

    int gid = blockIdx.x * TPB + t;
    int node = gid >> 3;
    int o = gid & 7;
    if (node >= n) return;
    float acc = bs[o];
    const float* xr = x + (long long)node * 64;
    #pragma unroll
    for (int k = 0; k < 64; ++k) acc = fmaf(xr[k], Ws[k * 8 + o], acc);
    out[(long long)node * 8 + o] = acc;
}

extern "C" void kernel_launch(void* const* d_in, const int* in_sizes, int n_in,
                              void* d_out, int out_size, void* d_ws, size_t ws_size,
                              hipStream_t stream) {
    const float* x  = (const float*)d_in[0];
    const void*  ei = d_in[1];
    const float* W[3]  = {(const float*)d_in[2], (const float*)d_in[4], (const float*)d_in[6]};
    const float* bv[3] = {(const float*)d_in[3], (const float*)d_in[5], (const float*)d_in[7]};
    const float* Wl = (const float*)d_in[8];
    const float* bl = (const float*)d_in[9];

    const long long E = in_sizes[1] / 2;                 // 800000
    const int dh = in_sizes[3];                          // 64
    const int din = in_sizes[2] / dh;                    // 64
    const int N = in_sizes[0] / din;                     // 50000

    // Workspace carve (256-aligned): ~42.5 MB total
    char* ws = (char*)d_ws;
    size_t off = 0;
    auto alloc = [&](size_t bytes) -> char* {
        char* r = ws + off;
        off += (bytes + 255) & ~(size_t)255;
        return r;
    };
    int*   flag    = (int*)  alloc(4);
    int*   deg     = (int*)  alloc((size_t)N * 4);
    int*   cursor  = (int*)  alloc((size_t)N * 4);
    int*   offsets = (int*)  alloc((size_t)N * 4);
    int*   bsums   = (int*)  alloc(4096);
    float* dis     = (float*)alloc((size_t)N * 4);
    int*   csr     = (int*)  alloc((size_t)E * 4);
    float* bufA    = (float*)alloc((size_t)N * 64 * 4);
    float* bufB    = (float*)alloc((size_t)N * 64 * 4);
    float* bufC    = (float*)alloc((size_t)N * 64 * 4);

    const int gN  = (N + TPB - 1) / TPB;                 // 196
    const int gE  = (int)((E + TPB - 1) / TPB);          // 3125

    // --- preprocessing: dtype flag, degrees, dis, CSR ---
    detect_idx<<<1, 64, 0, stream>>>((const unsigned int*)ei, flag);
    deg_init<<<gN, TPB, 0, stream>>>(deg, N);
    deg_count<<<gE, TPB, 0, stream>>>(ei, E, flag, deg);
    make_dis<<<gN, TPB, 0, stream>>>(deg, dis, N);
    scan_blocks<<<gN, TPB, 0, stream>>>(deg, offsets, bsums, N);
    scan_bsums<<<1, 64, 0, stream>>>(bsums, gN);
    add_bsums<<<gN, TPB, 0, stream>>>(offsets, bsums, cursor, N);
    fill_csr<<<gE, TPB, 0, stream>>>(ei, E, flag, cursor, csr);

    // --- 3 GCN layers ---
    const int gGemm   = (N + 3) / 4;                     // 12500
    const int gGather = (N * 16 + TPB - 1) / TPB;        // 3125
    const float* xin = x;
    float* outs[3] = {bufA, bufB, bufA};
    for (int L = 0; L < 3; ++L) {
        gemm_scale<<<gGemm, TPB, 0, stream>>>(xin, W[L], dis, bufC, N);
        gather_relu<<<gGather, TPB, 0, stream>>>(bufC, csr, offsets, deg, dis,
                                                 bv[L], outs[L], N);
        xin = outs[L];
    }

    // --- final linear ---
    const int gFin = (N * 8 + TPB - 1) / TPB;            // 1563
    final_lin<<<gFin, TPB, 0, stream>>>(xin, Wl, bl, (float*)d_out, N);
}

// Round 2
// 313.622 us; speedup vs baseline: 1.2274x; 1.2274x over previous
//
#include <hip/hip_runtime.h>

#define TPB 256

// ---------------------------------------------------------------------------
// Edge-index dtype detection: if edge_index is int64 (little-endian, values in
// [0,50000)), every odd 32-bit word is a zero high-word. If int32, odd words
// are real node ids (P[all 64 samples == 0] ~ (1/50000)^64 ~ 0).
// ---------------------------------------------------------------------------
__global__ void detect_idx(const unsigned int* w, int* flag) {
    __shared__ unsigned int s[64];
    int t = threadIdx.x;
    s[t] = w[2 * t + 1];
    __syncthreads();
    if (t == 0) {
        unsigned int acc = 0;
        for (int i = 0; i < 64; ++i) acc |= s[i];
        *flag = (acc == 0u) ? 1 : 0;   // 1 => int64, 0 => int32
    }
}

__device__ __forceinline__ int ld_idx(const void* p, long long i, int is64) {
    return is64 ? (int)((const long long*)p)[i] : ((const int*)p)[i];
}

// deg[v] = 1 (self loop) + in-degree
__global__ void deg_init(int* deg, int n) {
    int i = blockIdx.x * TPB + threadIdx.x;
    if (i < n) deg[i] = 1;
}

__global__ void deg_count(const void* ei, long long E, const int* flag, int* deg) {
    long long e = (long long)blockIdx.x * TPB + threadIdx.x;
    if (e < E) {
        int is64 = *flag;
        int d = ld_idx(ei, E + e, is64);
        atomicAdd(&deg[d], 1);
    }
}

// Exclusive scan of (deg[i]-1) = CSR row offsets; also emits dis = rsqrt(deg).
__global__ void scan_blocks(const int* deg, int* offsets, int* bsums,
                            float* dis, int n) {
    __shared__ int s[TPB];
    int tid = threadIdx.x;
    int i = blockIdx.x * TPB + tid;
    int dv = (i < n) ? deg[i] : 1;
    int v = dv - 1;
    s[tid] = v;
    __syncthreads();
    for (int off = 1; off < TPB; off <<= 1) {
        int t = 0;
        if (tid >= off) t = s[tid - off];
        __syncthreads();
        s[tid] += t;
        __syncthreads();
    }
    if (i < n) {
        offsets[i] = s[tid] - v;                 // exclusive within block
        dis[i] = rsqrtf((float)dv);
    }
    if (tid == TPB - 1) bsums[blockIdx.x] = s[tid];
}

__global__ void scan_bsums(int* bsums, int nb) {
    if (threadIdx.x == 0 && blockIdx.x == 0) {
        int acc = 0;
        for (int b = 0; b < nb; ++b) { int v = bsums[b]; bsums[b] = acc; acc += v; }
    }
}

__global__ void add_bsums(int* offsets, const int* bsums, int* cursor, int n) {
    int i = blockIdx.x * TPB + threadIdx.x;
    if (i < n) {
        int o = offsets[i] + bsums[blockIdx.x];
        offsets[i] = o;
        cursor[i] = o;
    }
}

__global__ void fill_csr(const void* ei, long long E, const int* flag,
                         int* cursor, int* csr) {
    long long e = (long long)blockIdx.x * TPB + threadIdx.x;
    if (e < E) {
        int is64 = *flag;
        int s = ld_idx(ei, e, is64);
        int d = ld_idx(ei, E + e, is64);
        int pos = atomicAdd(&cursor[d], 1);
        csr[pos] = s;
    }
}

// ---------------------------------------------------------------------------
// Cooperative gather: 16 lanes of a node-group batch-load 16 CSR indices in
// one coalesced read, broadcast via __shfl, then issue up to 16 INDEPENDENT
// float4 row loads (MLP ~16 instead of a serial idx->row dependent chain).
// All control conditions are group-uniform (cnt, rem), so shfl sources are
// always active lanes of the same group.
// ---------------------------------------------------------------------------
__device__ __forceinline__ float4 gather_rows(const float4* __restrict__ y4,
                                              const int* __restrict__ csr,
                                              int start, int cnt, int c,
                                              float4 acc) {
    const int base = threadIdx.x & 48;           // group base lane within wave
    int j = 0;
    while (j + 16 <= cnt) {
        int idx = csr[start + j + c];
        #pragma unroll
        for (int k = 0; k < 16; ++k) {
            int s = __shfl(idx, base + k);
            float4 v = y4[s * 16 + c];
            acc.x += v.x; acc.y += v.y; acc.z += v.z; acc.w += v.w;
        }
        j += 16;
    }
    int rem = cnt - j;                           // 0..15, group-uniform
    if (rem > 0) {
        int idx = (c < rem) ? csr[start + j + c] : 0;
        #pragma unroll
        for (int k = 0; k < 15; ++k) {
            if (k < rem) {
                int s = __shfl(idx, base + k);
                float4 v = y4[s * 16 + c];
                acc.x += v.x; acc.y += v.y; acc.z += v.z; acc.w += v.w;
            }
        }
    }
    return acc;
}

// ---------------------------------------------------------------------------
// Layer-0 GEMM: y[v] = dis[v] * (x[v] @ W).  16 nodes/block, 16 threads/node,
// each thread produces a float4 of outputs. W (16 KB) + h rows (padded) in LDS.
// ---------------------------------------------------------------------------
__global__ __launch_bounds__(TPB) void mm_first(const float* __restrict__ x,
                                                const float* __restrict__ W,
                                                const float* __restrict__ dis,
                                                float* __restrict__ yout, int n) {
    __shared__ float Ws[64 * 64];
    __shared__ float hs[16][68];                 // +4 pad kills bank conflicts
    int t = threadIdx.x;
    const float4* W4g = (const float4*)W;
    float4* Ws4 = (float4*)Ws;
    #pragma unroll
    for (int i = 0; i < 4; ++i) Ws4[t + i * TPB] = W4g[t + i * TPB];

    int ni = t >> 4, c = t & 15;
    int node = blockIdx.x * 16 + ni;
    float4 h = {0.f, 0.f, 0.f, 0.f};
    float dv = 0.f;
    if (node < n) {
        h = ((const float4*)x)[node * 16 + c];
        dv = dis[node];
    }
    *(float4*)&hs[ni][c * 4] = h;
    __syncthreads();

    float4 o = {0.f, 0.f, 0.f, 0.f};
    #pragma unroll
    for (int k = 0; k < 64; ++k) {
        float hv = hs[ni][k];
        float4 w = Ws4[k * 16 + c];
        o.x = fmaf(hv, w.x, o.x);
        o.y = fmaf(hv, w.y, o.y);
        o.z = fmaf(hv, w.z, o.z);
        o.w = fmaf(hv, w.w, o.w);
    }
    if (node < n) {
        float4 r = {o.x * dv, o.y * dv, o.z * dv, o.w * dv};
        ((float4*)yout)[node * 16 + c] = r;
    }
}

// ---------------------------------------------------------------------------
// Fused: h[v] = relu(dis[v]*(y[v] + sum_{in} y[src]) + b)   (gather+relu)
//        yout[v] = dis[v] * (h[v] @ W)                       (next-layer mm)
// ---------------------------------------------------------------------------
__global__ __launch_bounds__(TPB) void agg_mm(const float* __restrict__ y,
                                              const int* __restrict__ csr,
                                              const int* __restrict__ offsets,
                                              const int* __restrict__ deg,
                                              const float* __restrict__ dis,
                                              const float* __restrict__ b,
                                              const float* __restrict__ W,
                                              float* __restrict__ yout, int n) {
    __shared__ float Ws[64 * 64];
    __shared__ float hs[16][68];
    int t = threadIdx.x;
    const float4* W4g = (const float4*)W;
    float4* Ws4 = (float4*)Ws;
    #pragma unroll
    for (int i = 0; i < 4; ++i) Ws4[t + i * TPB] = W4g[t + i * TPB];

    int ni = t >> 4, c = t & 15;
    int node = blockIdx.x * 16 + ni;
    float4 h = {0.f, 0.f, 0.f, 0.f};
    float dv = 0.f;
    if (node < n) {
        const float4* y4 = (const float4*)y;
        float4 acc = y4[node * 16 + c];          // self-loop term
        int start = offsets[node];
        int cnt = deg[node] - 1;
        acc = gather_rows(y4, csr, start, cnt, c, acc);
        dv = dis[node];
        float4 bb = ((const float4*)b)[c];
        h.x = fmaxf(fmaf(dv, acc.x, bb.x), 0.f);
        h.y = fmaxf(fmaf(dv, acc.y, bb.y), 0.f);
        h.z = fmaxf(fmaf(dv, acc.z, bb.z), 0.f);
        h.w = fmaxf(fmaf(dv, acc.w, bb.w), 0.f);
    }
    *(float4*)&hs[ni][c * 4] = h;
    __syncthreads();

    float4 o = {0.f, 0.f, 0.f, 0.f};
    #pragma unroll
    for (int k = 0; k < 64; ++k) {
        float hv = hs[ni][k];
        float4 w = Ws4[k * 16 + c];
        o.x = fmaf(hv, w.x, o.x);
        o.y = fmaf(hv, w.y, o.y);
        o.z = fmaf(hv, w.z, o.z);
        o.w = fmaf(hv, w.w, o.w);
    }
    if (node < n) {
        float4 r = {o.x * dv, o.y * dv, o.z * dv, o.w * dv};
        ((float4*)yout)[node * 16 + c] = r;
    }
}

// ---------------------------------------------------------------------------
// Fused last layer: h = relu(dis*(agg y)+b2); out = h @ linW + linb  (64->8)
// ---------------------------------------------------------------------------
__global__ __launch_bounds__(TPB) void agg_final(const float* __restrict__ y,
                                                 const int* __restrict__ csr,
                                                 const int* __restrict__ offsets,
                                                 const int* __restrict__ deg,
                                                 const float* __restrict__ dis,
                                                 const float* __restrict__ b,
                                                 const float* __restrict__ Wl,
                                                 const float* __restrict__ bl,
                                                 float* __restrict__ out, int n) {
    __shared__ float Wls[64 * 8];
    __shared__ float bls[8];
    __shared__ float hs[16][68];
    int t = threadIdx.x;
    if (t < 128) ((float4*)Wls)[t] = ((const float4*)Wl)[t];
    if (t < 8) bls[t] = bl[t];

    int ni = t >> 4, c = t & 15;
    int node = blockIdx.x * 16 + ni;
    float4 h = {0.f, 0.f, 0.f, 0.f};
    if (node < n) {
        const float4* y4 = (const float4*)y;
        float4 acc = y4[node * 16 + c];
        int start = offsets[node];
        int cnt = deg[node] - 1;
        acc = gather_rows(y4, csr, start, cnt, c, acc);
        float dv = dis[node];
        float4 bb = ((const float4*)b)[c];
        h.x = fmaxf(fmaf(dv, acc.x, bb.x), 0.f);
        h.y = fmaxf(fmaf(dv, acc.y, bb.y), 0.f);
        h.z = fmaxf(fmaf(dv, acc.z, bb.z), 0.f);
        h.w = fmaxf(fmaf(dv, acc.w, bb.w), 0.f);
    }
    *(float4*)&hs[ni][c * 4] = h;
    __syncthreads();

    if (c < 8 && node < n) {
        float acc = bls[c];
        #pragma unroll
        for (int k = 0; k < 64; ++k)
            acc = fmaf(hs[ni][k], Wls[k * 8 + c], acc);
        out[node * 8 + c] = acc;
    }
}

extern "C" void kernel_launch(void* const* d_in, const int* in_sizes, int n_in,
                              void* d_out, int out_size, void* d_ws, size_t ws_size,
                              hipStream_t stream) {
    const float* x  = (const float*)d_in[0];
    const void*  ei = d_in[1];
    const float* W[3]  = {(const float*)d_in[2], (const float*)d_in[4], (const float*)d_in[6]};
    const float* bv[3] = {(const float*)d_in[3], (const float*)d_in[5], (const float*)d_in[7]};
    const float* Wl = (const float*)d_in[8];
    const float* bl = (const float*)d_in[9];

    const long long E = in_sizes[1] / 2;                 // 800000
    const int dh = in_sizes[3];                          // 64
    const int din = in_sizes[2] / dh;                    // 64
    const int N = in_sizes[0] / din;                     // 50000

    // Workspace carve (256-aligned): ~29.5 MB total
    char* ws = (char*)d_ws;
    size_t off = 0;
    auto alloc = [&](size_t bytes) -> char* {
        char* r = ws + off;
        off += (bytes + 255) & ~(size_t)255;
        return r;
    };
    int*   flag    = (int*)  alloc(4);
    int*   deg     = (int*)  alloc((size_t)N * 4);
    int*   cursor  = (int*)  alloc((size_t)N * 4);
    int*   offsets = (int*)  alloc((size_t)N * 4);
    int*   bsums   = (int*)  alloc(4096);
    float* dis     = (float*)alloc((size_t)N * 4);
    int*   csr     = (int*)  alloc((size_t)E * 4);
    float* bufA    = (float*)alloc((size_t)N * 64 * 4);
    float* bufB    = (float*)alloc((size_t)N * 64 * 4);

    const int gN  = (N + TPB - 1) / TPB;                 // 196
    const int gE  = (int)((E + TPB - 1) / TPB);          // 3125

    // --- preprocessing: dtype flag, degrees, dis, CSR ---
    detect_idx<<<1, 64, 0, stream>>>((const unsigned int*)ei, flag);
    deg_init<<<gN, TPB, 0, stream>>>(deg, N);
    deg_count<<<gE, TPB, 0, stream>>>(ei, E, flag, deg);
    scan_blocks<<<gN, TPB, 0, stream>>>(deg, offsets, bsums, dis, N);
    scan_bsums<<<1, 64, 0, stream>>>(bsums, gN);
    add_bsums<<<gN, TPB, 0, stream>>>(offsets, bsums, cursor, N);
    fill_csr<<<gE, TPB, 0, stream>>>(ei, E, flag, cursor, csr);

    // --- fused layers ---
    const int gL = (N + 15) / 16;                        // 3125
    // y0 = dis * (x @ W0)
    mm_first<<<gL, TPB, 0, stream>>>(x, W[0], dis, bufA, N);
    // x1 = relu(dis*(agg y0)+b0); y1 = dis*(x1 @ W1)
    agg_mm<<<gL, TPB, 0, stream>>>(bufA, csr, offsets, deg, dis, bv[0], W[1], bufB, N);
    // x2 = relu(dis*(agg y1)+b1); y2 = dis*(x2 @ W2)
    agg_mm<<<gL, TPB, 0, stream>>>(bufB, csr, offsets, deg, dis, bv[1], W[2], bufA, N);
    // x3 = relu(dis*(agg y2)+b2); out = x3 @ linW + linb
    agg_final<<<gL, TPB, 0, stream>>>(bufA, csr, offsets, deg, dis, bv[2], Wl, bl,
                                      (float*)d_out, N);
}

// Round 3
// 271.674 us; speedup vs baseline: 1.4170x; 1.1544x over previous
//
#include <hip/hip_runtime.h>

#define TPB 256

// Buckets: 256 nodes each (dst>>8). N=50000 -> nb=196 (must be <=256).

__device__ __forceinline__ int ld_idx(const void* p, long long i, int is64) {
    return is64 ? (int)((const long long*)p)[i] : ((const int*)p)[i];
}

// ---------------------------------------------------------------------------
// init: deg=0, bhist=0, and edge-dtype detection (block 0, wave 0).
// int64 edge_index => all odd 32-bit words of the first 64 entries are zero.
// ---------------------------------------------------------------------------
__global__ void init_all(const unsigned int* w, int* flag, int* deg,
                         int* bhist, int n) {
    int i = blockIdx.x * TPB + threadIdx.x;
    if (i < n) deg[i] = 0;
    if (i < 256) bhist[i] = 0;
    if (blockIdx.x == 0 && threadIdx.x < 64) {
        unsigned int v = w[2 * threadIdx.x + 1];
        unsigned long long m = __ballot(v != 0u);
        if (threadIdx.x == 0) *flag = (m == 0ull) ? 1 : 0;   // 1 => int64
    }
}

// ---------------------------------------------------------------------------
// One pass over dst: per-node in-degree (global atomics) + per-bucket
// histogram (LDS-aggregated, then 1 global atomic per block-bucket).
// ---------------------------------------------------------------------------
__global__ __launch_bounds__(TPB) void count_all(const void* ei, long long E,
                                                 const int* flag, int* deg,
                                                 int* bhist) {
    __shared__ int h[TPB];
    int t = threadIdx.x;
    h[t] = 0;
    __syncthreads();
    int is64 = *flag;
    long long stride = (long long)gridDim.x * TPB;
    for (long long e = (long long)blockIdx.x * TPB + t; e < E; e += stride) {
        int d = ld_idx(ei, E + e, is64);
        atomicAdd(&deg[d], 1);
        atomicAdd(&h[d >> 8], 1);
    }
    __syncthreads();
    if (h[t]) atomicAdd(&bhist[t], h[t]);
}

// Exclusive scan of bucket histogram -> boff[0..nb] and working cursor gcur.
__global__ void scan_small(const int* bhist, int* boff, int* gcur, int nb) {
    __shared__ int s[TPB];
    int t = threadIdx.x;
    int v = (t < nb) ? bhist[t] : 0;
    s[t] = v;
    __syncthreads();
    for (int off = 1; off < TPB; off <<= 1) {
        int u = 0;
        if (t >= off) u = s[t - off];
        __syncthreads();
        s[t] += u;
        __syncthreads();
    }
    if (t < nb) {
        int excl = s[t] - v;
        boff[t] = excl;
        gcur[t] = excl;
        if (t == nb - 1) boff[nb] = s[t];
    }
}

// ---------------------------------------------------------------------------
// Scatter (src,dst) pairs into bucket-sorted order. Each block reserves one
// contiguous range per bucket (LDS count -> 1 global atomic), so stores land
// as ~12-entry contiguous runs instead of isolated 4B scatters.
// ---------------------------------------------------------------------------
__global__ __launch_bounds__(TPB) void p3_scatter(const void* ei, long long E,
                                                  const int* flag, int* gcur,
                                                  int2* pairs) {
    __shared__ int cnt[TPB];
    __shared__ int cur2[TPB];
    int t = threadIdx.x;
    cnt[t] = 0;
    __syncthreads();
    int is64 = *flag;
    long long chunk = (E + gridDim.x - 1) / gridDim.x;
    long long s0 = (long long)blockIdx.x * chunk;
    long long s1 = (s0 + chunk < E) ? s0 + chunk : E;
    for (long long e = s0 + t; e < s1; e += TPB) {
        int d = ld_idx(ei, E + e, is64);
        atomicAdd(&cnt[d >> 8], 1);
    }
    __syncthreads();
    if (cnt[t]) cur2[t] = atomicAdd(&gcur[t], cnt[t]);
    __syncthreads();
    for (long long e = s0 + t; e < s1; e += TPB) {
        int sv = ld_idx(ei, e, is64);
        int d  = ld_idx(ei, E + e, is64);
        int pos = atomicAdd(&cur2[d >> 8], 1);
        pairs[pos] = make_int2(sv, d);
    }
}

// ---------------------------------------------------------------------------
// Final CSR fill: one block per bucket. LDS cursors (fast atomics); all csr
// stores land in this bucket's ~16KB CSR region -> L2-local, written once.
// ---------------------------------------------------------------------------
__global__ __launch_bounds__(TPB) void p4_fill(const int2* __restrict__ pairs,
                                               const int* __restrict__ boff,
                                               const int* __restrict__ offsets,
                                               int* __restrict__ csr, int n) {
    __shared__ int cur[TPB];
    int t = threadIdx.x;
    int b = blockIdx.x;
    int nbase = b << 8;
    int node = nbase + t;
    cur[t] = (node < n) ? offsets[node] : 0;
    __syncthreads();
    int e0 = boff[b], e1 = boff[b + 1];
    for (int e = e0 + t; e < e1; e += TPB) {
        int2 p = pairs[e];
        int pos = atomicAdd(&cur[p.y - nbase], 1);
        csr[pos] = p.x;
    }
}

// ---------------------------------------------------------------------------
// Node-offset scan (exclusive scan of in-degree) + dis = rsqrt(deg+1).
// ---------------------------------------------------------------------------
__global__ void scan_blocks(const int* deg, int* offsets, int* bsums,
                            float* dis, int n) {
    __shared__ int s[TPB];
    int tid = threadIdx.x;
    int i = blockIdx.x * TPB + tid;
    int dv = (i < n) ? deg[i] : 0;
    s[tid] = dv;
    __syncthreads();
    for (int off = 1; off < TPB; off <<= 1) {
        int u = 0;
        if (tid >= off) u = s[tid - off];
        __syncthreads();
        s[tid] += u;
        __syncthreads();
    }
    if (i < n) {
        offsets[i] = s[tid] - dv;                // exclusive within block
        dis[i] = rsqrtf((float)(dv + 1));        // +1 self loop
    }
    if (tid == TPB - 1) bsums[blockIdx.x] = s[tid];
}

// Parallel single-block scan of block sums (nb_blocks <= 256).
__global__ void scan_bsums(int* bsums, int nb) {
    __shared__ int s[TPB];
    int t = threadIdx.x;
    int v = (t < nb) ? bsums[t] : 0;
    s[t] = v;
    __syncthreads();
    for (int off = 1; off < TPB; off <<= 1) {
        int u = 0;
        if (t >= off) u = s[t - off];
        __syncthreads();
        s[t] += u;
        __syncthreads();
    }
    if (t < nb) bsums[t] = s[t] - v;             // exclusive
}

__global__ void add_bsums(int* offsets, const int* bsums, int n) {
    int i = blockIdx.x * TPB + threadIdx.x;
    if (i < n) offsets[i] += bsums[blockIdx.x];
}

// ---------------------------------------------------------------------------
// Cooperative gather: 16 lanes of a node-group batch-load 16 CSR indices in
// one coalesced read, broadcast via __shfl, then issue up to 16 INDEPENDENT
// float4 row loads (MLP ~16 instead of a serial idx->row dependent chain).
// ---------------------------------------------------------------------------
__device__ __forceinline__ float4 gather_rows(const float4* __restrict__ y4,
                                              const int* __restrict__ csr,
                                              int start, int cnt, int c,
                                              float4 acc) {
    const int base = threadIdx.x & 48;           // group base lane within wave
    int j = 0;
    while (j + 16 <= cnt) {
        int idx = csr[start + j + c];
        #pragma unroll
        for (int k = 0; k < 16; ++k) {
            int s = __shfl(idx, base + k);
            float4 v = y4[s * 16 + c];
            acc.x += v.x; acc.y += v.y; acc.z += v.z; acc.w += v.w;
        }
        j += 16;
    }
    int rem = cnt - j;                           // 0..15, group-uniform
    if (rem > 0) {
        int idx = (c < rem) ? csr[start + j + c] : 0;
        #pragma unroll
        for (int k = 0; k < 15; ++k) {
            if (k < rem) {
                int s = __shfl(idx, base + k);
                float4 v = y4[s * 16 + c];
                acc.x += v.x; acc.y += v.y; acc.z += v.z; acc.w += v.w;
            }
        }
    }
    return acc;
}

// ---------------------------------------------------------------------------
// Layer-0 GEMM: y[v] = dis[v] * (x[v] @ W).  16 nodes/block, 16 threads/node,
// each thread produces a float4 of outputs. W (16 KB) + h rows (padded) in LDS.
// ---------------------------------------------------------------------------
__global__ __launch_bounds__(TPB) void mm_first(const float* __restrict__ x,
                                                const float* __restrict__ W,
                                                const float* __restrict__ dis,
                                                float* __restrict__ yout, int n) {
    __shared__ float Ws[64 * 64];
    __shared__ float hs[16][68];                 // +4 pad kills bank conflicts
    int t = threadIdx.x;
    const float4* W4g = (const float4*)W;
    float4* Ws4 = (float4*)Ws;
    #pragma unroll
    for (int i = 0; i < 4; ++i) Ws4[t + i * TPB] = W4g[t + i * TPB];

    int ni = t >> 4, c = t & 15;
    int node = blockIdx.x * 16 + ni;
    float4 h = {0.f, 0.f, 0.f, 0.f};
    float dv = 0.f;
    if (node < n) {
        h = ((const float4*)x)[node * 16 + c];
        dv = dis[node];
    }
    *(float4*)&hs[ni][c * 4] = h;
    __syncthreads();

    float4 o = {0.f, 0.f, 0.f, 0.f};
    #pragma unroll
    for (int k = 0; k < 64; ++k) {
        float hv = hs[ni][k];
        float4 w = Ws4[k * 16 + c];
        o.x = fmaf(hv, w.x, o.x);
        o.y = fmaf(hv, w.y, o.y);
        o.z = fmaf(hv, w.z, o.z);
        o.w = fmaf(hv, w.w, o.w);
    }
    if (node < n) {
        float4 r = {o.x * dv, o.y * dv, o.z * dv, o.w * dv};
        ((float4*)yout)[node * 16 + c] = r;
    }
}

// ---------------------------------------------------------------------------
// Fused: h[v] = relu(dis[v]*(y[v] + sum_{in} y[src]) + b)   (gather+relu)
//        yout[v] = dis[v] * (h[v] @ W)                       (next-layer mm)
// ---------------------------------------------------------------------------
__global__ __launch_bounds__(TPB) void agg_mm(const float* __restrict__ y,
                                              const int* __restrict__ csr,
                                              const int* __restrict__ offsets,
                                              const int* __restrict__ deg,
                                              const float* __restrict__ dis,
                                              const float* __restrict__ b,
                                              const float* __restrict__ W,
                                              float* __restrict__ yout, int n) {
    __shared__ float Ws[64 * 64];
    __shared__ float hs[16][68];
    int t = threadIdx.x;
    const float4* W4g = (const float4*)W;
    float4* Ws4 = (float4*)Ws;
    #pragma unroll
    for (int i = 0; i < 4; ++i) Ws4[t + i * TPB] = W4g[t + i * TPB];

    int ni = t >> 4, c = t & 15;
    int node = blockIdx.x * 16 + ni;
    float4 h = {0.f, 0.f, 0.f, 0.f};
    float dv = 0.f;
    if (node < n) {
        const float4* y4 = (const float4*)y;
        float4 acc = y4[node * 16 + c];          // self-loop term
        int start = offsets[node];
        int cnt = deg[node];
        acc = gather_rows(y4, csr, start, cnt, c, acc);
        dv = dis[node];
        float4 bb = ((const float4*)b)[c];
        h.x = fmaxf(fmaf(dv, acc.x, bb.x), 0.f);
        h.y = fmaxf(fmaf(dv, acc.y, bb.y), 0.f);
        h.z = fmaxf(fmaf(dv, acc.z, bb.z), 0.f);
        h.w = fmaxf(fmaf(dv, acc.w, bb.w), 0.f);
    }
    *(float4*)&hs[ni][c * 4] = h;
    __syncthreads();

    float4 o = {0.f, 0.f, 0.f, 0.f};
    #pragma unroll
    for (int k = 0; k < 64; ++k) {
        float hv = hs[ni][k];
        float4 w = Ws4[k * 16 + c];
        o.x = fmaf(hv, w.x, o.x);
        o.y = fmaf(hv, w.y, o.y);
        o.z = fmaf(hv, w.z, o.z);
        o.w = fmaf(hv, w.w, o.w);
    }
    if (node < n) {
        float4 r = {o.x * dv, o.y * dv, o.z * dv, o.w * dv};
        ((float4*)yout)[node * 16 + c] = r;
    }
}

// ---------------------------------------------------------------------------
// Fused last layer: h = relu(dis*(agg y)+b2); out = h @ linW + linb  (64->8)
// ---------------------------------------------------------------------------
__global__ __launch_bounds__(TPB) void agg_final(const float* __restrict__ y,
                                                 const int* __restrict__ csr,
                                                 const int* __restrict__ offsets,
                                                 const int* __restrict__ deg,
                                                 const float* __restrict__ dis,
                                                 const float* __restrict__ b,
                                                 const float* __restrict__ Wl,
                                                 const float* __restrict__ bl,
                                                 float* __restrict__ out, int n) {
    __shared__ float Wls[64 * 8];
    __shared__ float bls[8];
    __shared__ float hs[16][68];
    int t = threadIdx.x;
    if (t < 128) ((float4*)Wls)[t] = ((const float4*)Wl)[t];
    if (t < 8) bls[t] = bl[t];

    int ni = t >> 4, c = t & 15;
    int node = blockIdx.x * 16 + ni;
    float4 h = {0.f, 0.f, 0.f, 0.f};
    if (node < n) {
        const float4* y4 = (const float4*)y;
        float4 acc = y4[node * 16 + c];
        int start = offsets[node];
        int cnt = deg[node];
        acc = gather_rows(y4, csr, start, cnt, c, acc);
        float dv = dis[node];
        float4 bb = ((const float4*)b)[c];
        h.x = fmaxf(fmaf(dv, acc.x, bb.x), 0.f);
        h.y = fmaxf(fmaf(dv, acc.y, bb.y), 0.f);
        h.z = fmaxf(fmaf(dv, acc.z, bb.z), 0.f);
        h.w = fmaxf(fmaf(dv, acc.w, bb.w), 0.f);
    }
    *(float4*)&hs[ni][c * 4] = h;
    __syncthreads();

    if (c < 8 && node < n) {
        float acc = bls[c];
        #pragma unroll
        for (int k = 0; k < 64; ++k)
            acc = fmaf(hs[ni][k], Wls[k * 8 + c], acc);
        out[node * 8 + c] = acc;
    }
}

extern "C" void kernel_launch(void* const* d_in, const int* in_sizes, int n_in,
                              void* d_out, int out_size, void* d_ws, size_t ws_size,
                              hipStream_t stream) {
    const float* x  = (const float*)d_in[0];
    const void*  ei = d_in[1];
    const float* W[3]  = {(const float*)d_in[2], (const float*)d_in[4], (const float*)d_in[6]};
    const float* bv[3] = {(const float*)d_in[3], (const float*)d_in[5], (const float*)d_in[7]};
    const float* Wl = (const float*)d_in[8];
    const float* bl = (const float*)d_in[9];

    const long long E = in_sizes[1] / 2;                 // 800000
    const int dh = in_sizes[3];                          // 64
    const int din = in_sizes[2] / dh;                    // 64
    const int N = in_sizes[0] / din;                     // 50000
    const int nb = (N + 255) >> 8;                       // 196 buckets

    // Workspace carve (256-aligned): ~36 MB total
    char* ws = (char*)d_ws;
    size_t off = 0;
    auto alloc = [&](size_t bytes) -> char* {
        char* r = ws + off;
        off += (bytes + 255) & ~(size_t)255;
        return r;
    };
    int*   flag    = (int*)  alloc(4);
    int*   deg     = (int*)  alloc((size_t)N * 4);
    int*   offsets = (int*)  alloc((size_t)N * 4);
    int*   bsums   = (int*)  alloc(4096);
    int*   bhist   = (int*)  alloc(1024);
    int*   boff    = (int*)  alloc(1040);
    int*   gcur    = (int*)  alloc(1024);
    float* dis     = (float*)alloc((size_t)N * 4);
    int*   csr     = (int*)  alloc((size_t)E * 4);
    int2*  pairs   = (int2*) alloc((size_t)E * 8);
    float* bufA    = (float*)alloc((size_t)N * 64 * 4);
    float* bufB    = (float*)alloc((size_t)N * 64 * 4);

    const int gN = (N + TPB - 1) / TPB;                  // 196

    // --- preprocessing: degrees + dis + bucketed CSR build ---
    init_all<<<gN, TPB, 0, stream>>>((const unsigned int*)ei, flag, deg, bhist, N);
    count_all<<<256, TPB, 0, stream>>>(ei, E, flag, deg, bhist);
    scan_small<<<1, TPB, 0, stream>>>(bhist, boff, gcur, nb);
    scan_blocks<<<gN, TPB, 0, stream>>>(deg, offsets, bsums, dis, N);
    scan_bsums<<<1, TPB, 0, stream>>>(bsums, gN);
    add_bsums<<<gN, TPB, 0, stream>>>(offsets, bsums, N);
    p3_scatter<<<256, TPB, 0, stream>>>(ei, E, flag, gcur, pairs);
    p4_fill<<<nb, TPB, 0, stream>>>(pairs, boff, offsets, csr, N);

    // --- fused layers ---
    const int gL = (N + 15) / 16;                        // 3125
    mm_first<<<gL, TPB, 0, stream>>>(x, W[0], dis, bufA, N);
    agg_mm<<<gL, TPB, 0, stream>>>(bufA, csr, offsets, deg, dis, bv[0], W[1], bufB, N);
    agg_mm<<<gL, TPB, 0, stream>>>(bufB, csr, offsets, deg, dis, bv[1], W[2], bufA, N);
    agg_final<<<gL, TPB, 0, stream>>>(bufA, csr, offsets, deg, dis, bv[2], Wl, bl,
                                      (float*)d_out, N);
}

// Round 4
// 265.908 us; speedup vs baseline: 1.4477x; 1.0217x over previous
//
#include <hip/hip_runtime.h>
#include <hip/hip_fp16.h>

#define TPB 256

// Buckets: 256 nodes each (dst>>8). N=50000 -> nb=196 (must be <=256).
// scan_blocks blocks are exactly the buckets, so bucket histogram == bsums.

__device__ __forceinline__ int ld_idx(const void* p, long long i, int is64) {
    return is64 ? (int)((const long long*)p)[i] : ((const int*)p)[i];
}

// init: deg=0 + edge-dtype detection (int64 => odd 32-bit words all zero).
__global__ void init_all(const unsigned int* w, int* flag, int* deg, int n) {
    int i = blockIdx.x * TPB + threadIdx.x;
    if (i < n) deg[i] = 0;
    if (blockIdx.x == 0 && threadIdx.x < 64) {
        unsigned int v = w[2 * threadIdx.x + 1];
        unsigned long long m = __ballot(v != 0u);
        if (threadIdx.x == 0) *flag = (m == 0ull) ? 1 : 0;   // 1 => int64
    }
}

// One pass over dst: per-node in-degree (global atomics only).
__global__ __launch_bounds__(TPB) void count_all(const void* ei, long long E,
                                                 const int* flag, int* deg) {
    int t = threadIdx.x;
    int is64 = *flag;
    long long stride = (long long)gridDim.x * TPB;
    for (long long e = (long long)blockIdx.x * TPB + t; e < E; e += stride) {
        int d = ld_idx(ei, E + e, is64);
        atomicAdd(&deg[d], 1);
    }
}

// Node-offset scan (exclusive scan of in-degree) + dis = rsqrt(deg+1).
// Block b covers nodes [b*256, b*256+256) == bucket b; bsums[b] = bucket count.
__global__ void scan_blocks(const int* deg, int* offsets, int* bsums,
                            float* dis, int n) {
    __shared__ int s[TPB];
    int tid = threadIdx.x;
    int i = blockIdx.x * TPB + tid;
    int dv = (i < n) ? deg[i] : 0;
    s[tid] = dv;
    __syncthreads();
    for (int off = 1; off < TPB; off <<= 1) {
        int u = 0;
        if (tid >= off) u = s[tid - off];
        __syncthreads();
        s[tid] += u;
        __syncthreads();
    }
    if (i < n) {
        offsets[i] = s[tid] - dv;                // exclusive within block
        dis[i] = rsqrtf((float)(dv + 1));        // +1 self loop
    }
    if (tid == TPB - 1) bsums[blockIdx.x] = s[tid];
}

// Single-block scan of bucket sums -> block-offsets, bucket-offsets, cursors.
__global__ void scan_bsums(int* bsums, int* boff, int* gcur, int nb, int Ei) {
    __shared__ int s[TPB];
    int t = threadIdx.x;
    int v = (t < nb) ? bsums[t] : 0;
    s[t] = v;
    __syncthreads();
    for (int off = 1; off < TPB; off <<= 1) {
        int u = 0;
        if (t >= off) u = s[t - off];
        __syncthreads();
        s[t] += u;
        __syncthreads();
    }
    if (t < nb) {
        int excl = s[t] - v;
        bsums[t] = excl;
        boff[t] = excl;
        gcur[t] = excl;
    }
    if (t == 0) boff[nb] = Ei;
}

__global__ void add_bsums(int* offsets, const int* bsums, int n) {
    int i = blockIdx.x * TPB + threadIdx.x;
    if (i < n) offsets[i] += bsums[blockIdx.x];
}

// ---------------------------------------------------------------------------
// Scatter packed (src<<8 | dst&255) into bucket-sorted order. Each block
// reserves one contiguous range per bucket (LDS count -> 1 global atomic), so
// stores land as contiguous runs instead of isolated 4B scatters.
// ---------------------------------------------------------------------------
__global__ __launch_bounds__(TPB) void p3_scatter(const void* ei, long long E,
                                                  const int* flag, int* gcur,
                                                  int* pairs) {
    __shared__ int cnt[TPB];
    __shared__ int cur2[TPB];
    int t = threadIdx.x;
    cnt[t] = 0;
    __syncthreads();
    int is64 = *flag;
    long long chunk = (E + gridDim.x - 1) / gridDim.x;
    long long s0 = (long long)blockIdx.x * chunk;
    long long s1 = (s0 + chunk < E) ? s0 + chunk : E;
    for (long long e = s0 + t; e < s1; e += TPB) {
        int d = ld_idx(ei, E + e, is64);
        atomicAdd(&cnt[d >> 8], 1);
    }
    __syncthreads();
    if (cnt[t]) cur2[t] = atomicAdd(&gcur[t], cnt[t]);
    __syncthreads();
    for (long long e = s0 + t; e < s1; e += TPB) {
        int sv = ld_idx(ei, e, is64);
        int d  = ld_idx(ei, E + e, is64);
        int pos = atomicAdd(&cur2[d >> 8], 1);
        pairs[pos] = (sv << 8) | (d & 255);
    }
}

// Final CSR fill: one block per bucket; LDS cursors; csr stores land in this
// bucket's own region -> L2-local, written once.
__global__ __launch_bounds__(TPB) void p4_fill(const int* __restrict__ pairs,
                                               const int* __restrict__ boff,
                                               const int* __restrict__ offsets,
                                               int* __restrict__ csr, int n) {
    __shared__ int cur[TPB];
    int t = threadIdx.x;
    int b = blockIdx.x;
    int node = (b << 8) + t;
    cur[t] = (node < n) ? offsets[node] : 0;
    __syncthreads();
    int e0 = boff[b], e1 = boff[b + 1];
    for (int e = e0 + t; e < e1; e += TPB) {
        int p = pairs[e];
        int pos = atomicAdd(&cur[p & 255], 1);
        csr[pos] = p >> 8;
    }
}

// ---------------------------------------------------------------------------
// fp16 row helpers: rows are 64 halves = 128 B = 16 x ushort4.
// ---------------------------------------------------------------------------
__device__ __forceinline__ float4 h4_to_f4(ushort4 v) {
    float4 r;
    r.x = __half2float(__ushort_as_half(v.x));
    r.y = __half2float(__ushort_as_half(v.y));
    r.z = __half2float(__ushort_as_half(v.z));
    r.w = __half2float(__ushort_as_half(v.w));
    return r;
}

__device__ __forceinline__ ushort4 f4_to_h4(float4 v) {
    ushort4 r;
    r.x = __half_as_ushort(__float2half_rn(v.x));
    r.y = __half_as_ushort(__float2half_rn(v.y));
    r.z = __half_as_ushort(__float2half_rn(v.z));
    r.w = __half_as_ushort(__float2half_rn(v.w));
    return r;
}

// ---------------------------------------------------------------------------
// Cooperative gather (fp16 rows): 16 lanes of a node-group batch-load 16 CSR
// indices in one coalesced read, broadcast via __shfl, then issue up to 16
// INDEPENDENT 8B row-chunk loads (MLP ~16, no serial idx->row chain).
// ---------------------------------------------------------------------------
__device__ __forceinline__ float4 gather_rows(const ushort4* __restrict__ y4,
                                              const int* __restrict__ csr,
                                              int start, int cnt, int c,
                                              float4 acc) {
    const int base = threadIdx.x & 48;           // group base lane within wave
    int j = 0;
    while (j + 16 <= cnt) {
        int idx = csr[start + j + c];
        #pragma unroll
        for (int k = 0; k < 16; ++k) {
            int s = __shfl(idx, base + k);
            float4 v = h4_to_f4(y4[s * 16 + c]);
            acc.x += v.x; acc.y += v.y; acc.z += v.z; acc.w += v.w;
        }
        j += 16;
    }
    int rem = cnt - j;                           // 0..15, group-uniform
    if (rem > 0) {
        int idx = (c < rem) ? csr[start + j + c] : 0;
        #pragma unroll
        for (int k = 0; k < 15; ++k) {
            if (k < rem) {
                int s = __shfl(idx, base + k);
                float4 v = h4_to_f4(y4[s * 16 + c]);
                acc.x += v.x; acc.y += v.y; acc.z += v.z; acc.w += v.w;
            }
        }
    }
    return acc;
}

// ---------------------------------------------------------------------------
// Layer-0 GEMM: y[v] = fp16(dis[v] * (x[v] @ W)).  16 nodes/block, 16
// threads/node, each thread produces a float4 of outputs. W in LDS.
// ---------------------------------------------------------------------------
__global__ __launch_bounds__(TPB) void mm_first(const float* __restrict__ x,
                                                const float* __restrict__ W,
                                                const float* __restrict__ dis,
                                                ushort4* __restrict__ yout, int n) {
    __shared__ float Ws[64 * 64];
    __shared__ float hs[16][68];                 // +4 pad kills bank conflicts
    int t = threadIdx.x;
    const float4* W4g = (const float4*)W;
    float4* Ws4 = (float4*)Ws;
    #pragma unroll
    for (int i = 0; i < 4; ++i) Ws4[t + i * TPB] = W4g[t + i * TPB];

    int ni = t >> 4, c = t & 15;
    int node = blockIdx.x * 16 + ni;
    float4 h = {0.f, 0.f, 0.f, 0.f};
    float dv = 0.f;
    if (node < n) {
        h = ((const float4*)x)[node * 16 + c];
        dv = dis[node];
    }
    *(float4*)&hs[ni][c * 4] = h;
    __syncthreads();

    float4 o = {0.f, 0.f, 0.f, 0.f};
    #pragma unroll
    for (int k = 0; k < 64; ++k) {
        float hv = hs[ni][k];
        float4 w = Ws4[k * 16 + c];
        o.x = fmaf(hv, w.x, o.x);
        o.y = fmaf(hv, w.y, o.y);
        o.z = fmaf(hv, w.z, o.z);
        o.w = fmaf(hv, w.w, o.w);
    }
    if (node < n) {
        float4 r = {o.x * dv, o.y * dv, o.z * dv, o.w * dv};
        yout[node * 16 + c] = f4_to_h4(r);
    }
}

// ---------------------------------------------------------------------------
// Fused: h[v] = relu(dis[v]*(y[v] + sum_{in} y[src]) + b)   (fp16 gather)
//        yout[v] = fp16(dis[v] * (h[v] @ W))                (next-layer mm)
// ---------------------------------------------------------------------------
__global__ __launch_bounds__(TPB) void agg_mm(const ushort4* __restrict__ y,
                                              const int* __restrict__ csr,
                                              const int* __restrict__ offsets,
                                              const int* __restrict__ deg,
                                              const float* __restrict__ dis,
                                              const float* __restrict__ b,
                                              const float* __restrict__ W,
                                              ushort4* __restrict__ yout, int n) {
    __shared__ float Ws[64 * 64];
    __shared__ float hs[16][68];
    int t = threadIdx.x;
    const float4* W4g = (const float4*)W;
    float4* Ws4 = (float4*)Ws;
    #pragma unroll
    for (int i = 0; i < 4; ++i) Ws4[t + i * TPB] = W4g[t + i * TPB];

    int ni = t >> 4, c = t & 15;
    int node = blockIdx.x * 16 + ni;
    float4 h = {0.f, 0.f, 0.f, 0.f};
    float dv = 0.f;
    if (node < n) {
        float4 acc = h4_to_f4(y[node * 16 + c]);     // self-loop term
        int start = offsets[node];
        int cnt = deg[node];
        acc = gather_rows(y, csr, start, cnt, c, acc);
        dv = dis[node];
        float4 bb = ((const float4*)b)[c];
        h.x = fmaxf(fmaf(dv, acc.x, bb.x), 0.f);
        h.y = fmaxf(fmaf(dv, acc.y, bb.y), 0.f);
        h.z = fmaxf(fmaf(dv, acc.z, bb.z), 0.f);
        h.w = fmaxf(fmaf(dv, acc.w, bb.w), 0.f);
    }
    *(float4*)&hs[ni][c * 4] = h;
    __syncthreads();

    float4 o = {0.f, 0.f, 0.f, 0.f};
    #pragma unroll
    for (int k = 0; k < 64; ++k) {
        float hv = hs[ni][k];
        float4 w = Ws4[k * 16 + c];
        o.x = fmaf(hv, w.x, o.x);
        o.y = fmaf(hv, w.y, o.y);
        o.z = fmaf(hv, w.z, o.z);
        o.w = fmaf(hv, w.w, o.w);
    }
    if (node < n) {
        float4 r = {o.x * dv, o.y * dv, o.z * dv, o.w * dv};
        yout[node * 16 + c] = f4_to_h4(r);
    }
}

// ---------------------------------------------------------------------------
// Fused last layer: h = relu(dis*(agg y)+b2); out = h @ linW + linb  (64->8)
// ---------------------------------------------------------------------------
__global__ __launch_bounds__(TPB) void agg_final(const ushort4* __restrict__ y,
                                                 const int* __restrict__ csr,
                                                 const int* __restrict__ offsets,
                                                 const int* __restrict__ deg,
                                                 const float* __restrict__ dis,
                                                 const float* __restrict__ b,
                                                 const float* __restrict__ Wl,
                                                 const float* __restrict__ bl,
                                                 float* __restrict__ out, int n) {
    __shared__ float Wls[64 * 8];
    __shared__ float bls[8];
    __shared__ float hs[16][68];
    int t = threadIdx.x;
    if (t < 128) ((float4*)Wls)[t] = ((const float4*)Wl)[t];
    if (t < 8) bls[t] = bl[t];

    int ni = t >> 4, c = t & 15;
    int node = blockIdx.x * 16 + ni;
    float4 h = {0.f, 0.f, 0.f, 0.f};
    if (node < n) {
        float4 acc = h4_to_f4(y[node * 16 + c]);
        int start = offsets[node];
        int cnt = deg[node];
        acc = gather_rows(y, csr, start, cnt, c, acc);
        float dv = dis[node];
        float4 bb = ((const float4*)b)[c];
        h.x = fmaxf(fmaf(dv, acc.x, bb.x), 0.f);
        h.y = fmaxf(fmaf(dv, acc.y, bb.y), 0.f);
        h.z = fmaxf(fmaf(dv, acc.z, bb.z), 0.f);
        h.w = fmaxf(fmaf(dv, acc.w, bb.w), 0.f);
    }
    *(float4*)&hs[ni][c * 4] = h;
    __syncthreads();

    if (c < 8 && node < n) {
        float acc = bls[c];
        #pragma unroll
        for (int k = 0; k < 64; ++k)
            acc = fmaf(hs[ni][k], Wls[k * 8 + c], acc);
        out[node * 8 + c] = acc;
    }
}

extern "C" void kernel_launch(void* const* d_in, const int* in_sizes, int n_in,
                              void* d_out, int out_size, void* d_ws, size_t ws_size,
                              hipStream_t stream) {
    const float* x  = (const float*)d_in[0];
    const void*  ei = d_in[1];
    const float* W[3]  = {(const float*)d_in[2], (const float*)d_in[4], (const float*)d_in[6]};
    const float* bv[3] = {(const float*)d_in[3], (const float*)d_in[5], (const float*)d_in[7]};
    const float* Wl = (const float*)d_in[8];
    const float* bl = (const float*)d_in[9];

    const long long E = in_sizes[1] / 2;                 // 800000
    const int dh = in_sizes[3];                          // 64
    const int din = in_sizes[2] / dh;                    // 64
    const int N = in_sizes[0] / din;                     // 50000
    const int nb = (N + 255) >> 8;                       // 196 buckets

    // Workspace carve (256-aligned): ~20 MB total
    char* ws = (char*)d_ws;
    size_t off = 0;
    auto alloc = [&](size_t bytes) -> char* {
        char* r = ws + off;
        off += (bytes + 255) & ~(size_t)255;
        return r;
    };
    int*     flag    = (int*)    alloc(4);
    int*     deg     = (int*)    alloc((size_t)N * 4);
    int*     offsets = (int*)    alloc((size_t)N * 4);
    int*     bsums   = (int*)    alloc(4096);
    int*     boff    = (int*)    alloc(1040);
    int*     gcur    = (int*)    alloc(1024);
    float*   dis     = (float*)  alloc((size_t)N * 4);
    int*     csr     = (int*)    alloc((size_t)E * 4);
    int*     pairs   = (int*)    alloc((size_t)E * 4);
    ushort4* ybA     = (ushort4*)alloc((size_t)N * 64 * 2);   // fp16 rows
    ushort4* ybB     = (ushort4*)alloc((size_t)N * 64 * 2);

    const int gN = (N + TPB - 1) / TPB;                  // 196 (== nb)

    // --- preprocessing: degrees + dis + bucketed CSR build ---
    init_all<<<gN, TPB, 0, stream>>>((const unsigned int*)ei, flag, deg, N);
    count_all<<<256, TPB, 0, stream>>>(ei, E, flag, deg);
    scan_blocks<<<gN, TPB, 0, stream>>>(deg, offsets, bsums, dis, N);
    scan_bsums<<<1, TPB, 0, stream>>>(bsums, boff, gcur, nb, (int)E);
    add_bsums<<<gN, TPB, 0, stream>>>(offsets, bsums, N);
    p3_scatter<<<256, TPB, 0, stream>>>(ei, E, flag, gcur, pairs);
    p4_fill<<<nb, TPB, 0, stream>>>(pairs, boff, offsets, csr, N);

    // --- fused layers ---
    const int gL = (N + 15) / 16;                        // 3125
    mm_first<<<gL, TPB, 0, stream>>>(x, W[0], dis, ybA, N);
    agg_mm<<<gL, TPB, 0, stream>>>(ybA, csr, offsets, deg, dis, bv[0], W[1], ybB, N);
    agg_mm<<<gL, TPB, 0, stream>>>(ybB, csr, offsets, deg, dis, bv[1], W[2], ybA, N);
    agg_final<<<gL, TPB, 0, stream>>>(ybA, csr, offsets, deg, dis, bv[2], Wl, bl,
                                      (float*)d_out, N);
}

// Round 5
// 224.211 us; speedup vs baseline: 1.7169x; 1.1860x over previous
//
#include <hip/hip_runtime.h>
#include <hip/hip_fp16.h>

#define TPB 256
#define CAP 8192           // slack entries per 256-node bucket (avg fill ~4082)
#define CAPSH 13           // log2(CAP)

// Buckets: 256 nodes each (dst>>8). N=50000 -> nb=196 (must be <=256).
// Bucket b owns pairs[b*CAP .. b*CAP+CAP) and csr[b*CAP .. b*CAP+CAP),
// so no cross-bucket exclusive scan is needed anywhere.

__device__ __forceinline__ int ld_idx(const void* p, long long i, int is64) {
    return is64 ? (int)((const long long*)p)[i] : ((const int*)p)[i];
}

// Single block: edge-dtype detection + gcur[b] = b*CAP.
// int64 edge_index => all odd 32-bit words of first 64 entries are zero.
__global__ void init_all(const unsigned int* w, int* flag, int* gcur) {
    int t = threadIdx.x;
    gcur[t] = t << CAPSH;
    if (t < 64) {
        unsigned int v = w[2 * t + 1];
        unsigned long long m = __ballot(v != 0u);
        if (t == 0) *flag = (m == 0ull) ? 1 : 0;   // 1 => int64
    }
}

// ---------------------------------------------------------------------------
// Scatter packed (src<<8 | dst&255) into per-bucket slack regions. Each block
// counts its chunk's bucket histogram in LDS, reserves one contiguous range
// per non-empty bucket (1 global atomic each, <=196/block = 50k total), then
// scatters as contiguous runs.
// ---------------------------------------------------------------------------
__global__ __launch_bounds__(TPB) void p3_scatter(const void* ei, long long E,
                                                  const int* flag, int* gcur,
                                                  int* pairs) {
    __shared__ int cnt[TPB];
    __shared__ int cur2[TPB];
    int t = threadIdx.x;
    cnt[t] = 0;
    __syncthreads();
    int is64 = *flag;
    long long chunk = (E + gridDim.x - 1) / gridDim.x;
    long long s0 = (long long)blockIdx.x * chunk;
    long long s1 = (s0 + chunk < E) ? s0 + chunk : E;
    for (long long e = s0 + t; e < s1; e += TPB) {
        int d = ld_idx(ei, E + e, is64);
        atomicAdd(&cnt[d >> 8], 1);
    }
    __syncthreads();
    if (cnt[t]) cur2[t] = atomicAdd(&gcur[t], cnt[t]);
    __syncthreads();
    for (long long e = s0 + t; e < s1; e += TPB) {
        int sv = ld_idx(ei, e, is64);
        int d  = ld_idx(ei, E + e, is64);
        int pos = atomicAdd(&cur2[d >> 8], 1);
        pairs[pos] = (sv << 8) | (d & 255);
    }
}

// ---------------------------------------------------------------------------
// One block per bucket: count per-node degree from bucket-local pairs (LDS
// atomics), 256-wide LDS scan -> per-node offsets (absolute, bucket-local
// base b*CAP), emit deg/dis/offsets, then scatter csr via LDS cursors.
// All global traffic is bucket-local (L2-resident) and written once.
// ---------------------------------------------------------------------------
__global__ __launch_bounds__(TPB) void p4_fill(const int* __restrict__ pairs,
                                               const int* __restrict__ gcur,
                                               int* __restrict__ deg,
                                               float* __restrict__ dis,
                                               int* __restrict__ offsets,
                                               int* __restrict__ csr, int n) {
    __shared__ int ldeg[TPB];
    __shared__ int s[TPB];
    __shared__ int cur[TPB];
    int t = threadIdx.x;
    int b = blockIdx.x;
    int base = b << CAPSH;
    int ecnt = gcur[b] - base;                   // edges in this bucket
    ldeg[t] = 0;
    __syncthreads();
    for (int e = base + t; e < base + ecnt; e += TPB)
        atomicAdd(&ldeg[pairs[e] & 255], 1);
    __syncthreads();
    int dv = ldeg[t];
    s[t] = dv;
    __syncthreads();
    for (int off = 1; off < TPB; off <<= 1) {
        int u = 0;
        if (t >= off) u = s[t - off];
        __syncthreads();
        s[t] += u;
        __syncthreads();
    }
    int o = base + s[t] - dv;                    // absolute exclusive offset
    cur[t] = o;
    int node = (b << 8) + t;
    if (node < n) {
        deg[node] = dv;
        dis[node] = rsqrtf((float)(dv + 1));     // +1 self loop
        offsets[node] = o;
    }
    __syncthreads();
    for (int e = base + t; e < base + ecnt; e += TPB) {
        int p = pairs[e];
        int pos = atomicAdd(&cur[p & 255], 1);
        csr[pos] = p >> 8;
    }
}

// ---------------------------------------------------------------------------
// fp16 row helpers: rows are 64 halves = 128 B = 16 x ushort4.
// ---------------------------------------------------------------------------
__device__ __forceinline__ float4 h4_to_f4(ushort4 v) {
    float4 r;
    r.x = __half2float(__ushort_as_half(v.x));
    r.y = __half2float(__ushort_as_half(v.y));
    r.z = __half2float(__ushort_as_half(v.z));
    r.w = __half2float(__ushort_as_half(v.w));
    return r;
}

__device__ __forceinline__ ushort4 f4_to_h4(float4 v) {
    ushort4 r;
    r.x = __half_as_ushort(__float2half_rn(v.x));
    r.y = __half_as_ushort(__float2half_rn(v.y));
    r.z = __half_as_ushort(__float2half_rn(v.z));
    r.w = __half_as_ushort(__float2half_rn(v.w));
    return r;
}

// ---------------------------------------------------------------------------
// Cooperative gather (fp16 rows): 16 lanes of a node-group batch-load 16 CSR
// indices in one coalesced read, broadcast via __shfl, then issue up to 16
// INDEPENDENT 8B row-chunk loads (MLP ~16, no serial idx->row chain).
// ---------------------------------------------------------------------------
__device__ __forceinline__ float4 gather_rows(const ushort4* __restrict__ y4,
                                              const int* __restrict__ csr,
                                              int start, int cnt, int c,
                                              float4 acc) {
    const int base = threadIdx.x & 48;           // group base lane within wave
    int j = 0;
    while (j + 16 <= cnt) {
        int idx = csr[start + j + c];
        #pragma unroll
        for (int k = 0; k < 16; ++k) {
            int s = __shfl(idx, base + k);
            float4 v = h4_to_f4(y4[s * 16 + c]);
            acc.x += v.x; acc.y += v.y; acc.z += v.z; acc.w += v.w;
        }
        j += 16;
    }
    int rem = cnt - j;                           // 0..15, group-uniform
    if (rem > 0) {
        int idx = (c < rem) ? csr[start + j + c] : 0;
        #pragma unroll
        for (int k = 0; k < 15; ++k) {
            if (k < rem) {
                int s = __shfl(idx, base + k);
                float4 v = h4_to_f4(y4[s * 16 + c]);
                acc.x += v.x; acc.y += v.y; acc.z += v.z; acc.w += v.w;
            }
        }
    }
    return acc;
}

// ---------------------------------------------------------------------------
// Layer-0 GEMM: y[v] = fp16(dis[v] * (x[v] @ W)).  16 nodes/block, 16
// threads/node, each thread produces a float4 of outputs. W in LDS.
// ---------------------------------------------------------------------------
__global__ __launch_bounds__(TPB) void mm_first(const float* __restrict__ x,
                                                const float* __restrict__ W,
                                                const float* __restrict__ dis,
                                                ushort4* __restrict__ yout, int n) {
    __shared__ float Ws[64 * 64];
    __shared__ float hs[16][68];                 // +4 pad kills bank conflicts
    int t = threadIdx.x;
    const float4* W4g = (const float4*)W;
    float4* Ws4 = (float4*)Ws;
    #pragma unroll
    for (int i = 0; i < 4; ++i) Ws4[t + i * TPB] = W4g[t + i * TPB];

    int ni = t >> 4, c = t & 15;
    int node = blockIdx.x * 16 + ni;
    float4 h = {0.f, 0.f, 0.f, 0.f};
    float dv = 0.f;
    if (node < n) {
        h = ((const float4*)x)[node * 16 + c];
        dv = dis[node];
    }
    *(float4*)&hs[ni][c * 4] = h;
    __syncthreads();

    float4 o = {0.f, 0.f, 0.f, 0.f};
    #pragma unroll
    for (int k = 0; k < 64; ++k) {
        float hv = hs[ni][k];
        float4 w = Ws4[k * 16 + c];
        o.x = fmaf(hv, w.x, o.x);
        o.y = fmaf(hv, w.y, o.y);
        o.z = fmaf(hv, w.z, o.z);
        o.w = fmaf(hv, w.w, o.w);
    }
    if (node < n) {
        float4 r = {o.x * dv, o.y * dv, o.z * dv, o.w * dv};
        yout[node * 16 + c] = f4_to_h4(r);
    }
}

// ---------------------------------------------------------------------------
// Fused: h[v] = relu(dis[v]*(y[v] + sum_{in} y[src]) + b)   (fp16 gather)
//        yout[v] = fp16(dis[v] * (h[v] @ W))                (next-layer mm)
// ---------------------------------------------------------------------------
__global__ __launch_bounds__(TPB) void agg_mm(const ushort4* __restrict__ y,
                                              const int* __restrict__ csr,
                                              const int* __restrict__ offsets,
                                              const int* __restrict__ deg,
                                              const float* __restrict__ dis,
                                              const float* __restrict__ b,
                                              const float* __restrict__ W,
                                              ushort4* __restrict__ yout, int n) {
    __shared__ float Ws[64 * 64];
    __shared__ float hs[16][68];
    int t = threadIdx.x;
    const float4* W4g = (const float4*)W;
    float4* Ws4 = (float4*)Ws;
    #pragma unroll
    for (int i = 0; i < 4; ++i) Ws4[t + i * TPB] = W4g[t + i * TPB];

    int ni = t >> 4, c = t & 15;
    int node = blockIdx.x * 16 + ni;
    float4 h = {0.f, 0.f, 0.f, 0.f};
    float dv = 0.f;
    if (node < n) {
        float4 acc = h4_to_f4(y[node * 16 + c]);     // self-loop term
        int start = offsets[node];
        int cnt = deg[node];
        acc = gather_rows(y, csr, start, cnt, c, acc);
        dv = dis[node];
        float4 bb = ((const float4*)b)[c];
        h.x = fmaxf(fmaf(dv, acc.x, bb.x), 0.f);
        h.y = fmaxf(fmaf(dv, acc.y, bb.y), 0.f);
        h.z = fmaxf(fmaf(dv, acc.z, bb.z), 0.f);
        h.w = fmaxf(fmaf(dv, acc.w, bb.w), 0.f);
    }
    *(float4*)&hs[ni][c * 4] = h;
    __syncthreads();

    float4 o = {0.f, 0.f, 0.f, 0.f};
    #pragma unroll
    for (int k = 0; k < 64; ++k) {
        float hv = hs[ni][k];
        float4 w = Ws4[k * 16 + c];
        o.x = fmaf(hv, w.x, o.x);
        o.y = fmaf(hv, w.y, o.y);
        o.z = fmaf(hv, w.z, o.z);
        o.w = fmaf(hv, w.w, o.w);
    }
    if (node < n) {
        float4 r = {o.x * dv, o.y * dv, o.z * dv, o.w * dv};
        yout[node * 16 + c] = f4_to_h4(r);
    }
}

// ---------------------------------------------------------------------------
// Fused last layer: h = relu(dis*(agg y)+b2); out = h @ linW + linb  (64->8)
// ---------------------------------------------------------------------------
__global__ __launch_bounds__(TPB) void agg_final(const ushort4* __restrict__ y,
                                                 const int* __restrict__ csr,
                                                 const int* __restrict__ offsets,
                                                 const int* __restrict__ deg,
                                                 const float* __restrict__ dis,
                                                 const float* __restrict__ b,
                                                 const float* __restrict__ Wl,
                                                 const float* __restrict__ bl,
                                                 float* __restrict__ out, int n) {
    __shared__ float Wls[64 * 8];
    __shared__ float bls[8];
    __shared__ float hs[16][68];
    int t = threadIdx.x;
    if (t < 128) ((float4*)Wls)[t] = ((const float4*)Wl)[t];
    if (t < 8) bls[t] = bl[t];

    int ni = t >> 4, c = t & 15;
    int node = blockIdx.x * 16 + ni;
    float4 h = {0.f, 0.f, 0.f, 0.f};
    if (node < n) {
        float4 acc = h4_to_f4(y[node * 16 + c]);
        int start = offsets[node];
        int cnt = deg[node];
        acc = gather_rows(y, csr, start, cnt, c, acc);
        float dv = dis[node];
        float4 bb = ((const float4*)b)[c];
        h.x = fmaxf(fmaf(dv, acc.x, bb.x), 0.f);
        h.y = fmaxf(fmaf(dv, acc.y, bb.y), 0.f);
        h.z = fmaxf(fmaf(dv, acc.z, bb.z), 0.f);
        h.w = fmaxf(fmaf(dv, acc.w, bb.w), 0.f);
    }
    *(float4*)&hs[ni][c * 4] = h;
    __syncthreads();

    if (c < 8 && node < n) {
        float acc = bls[c];
        #pragma unroll
        for (int k = 0; k < 64; ++k)
            acc = fmaf(hs[ni][k], Wls[k * 8 + c], acc);
        out[node * 8 + c] = acc;
    }
}

extern "C" void kernel_launch(void* const* d_in, const int* in_sizes, int n_in,
                              void* d_out, int out_size, void* d_ws, size_t ws_size,
                              hipStream_t stream) {
    const float* x  = (const float*)d_in[0];
    const void*  ei = d_in[1];
    const float* W[3]  = {(const float*)d_in[2], (const float*)d_in[4], (const float*)d_in[6]};
    const float* bv[3] = {(const float*)d_in[3], (const float*)d_in[5], (const float*)d_in[7]};
    const float* Wl = (const float*)d_in[8];
    const float* bl = (const float*)d_in[9];

    const long long E = in_sizes[1] / 2;                 // 800000
    const int dh = in_sizes[3];                          // 64
    const int din = in_sizes[2] / dh;                    // 64
    const int N = in_sizes[0] / din;                     // 50000
    const int nb = (N + 255) >> 8;                       // 196 buckets

    // Workspace carve (256-aligned): ~27 MB total
    char* ws = (char*)d_ws;
    size_t off = 0;
    auto alloc = [&](size_t bytes) -> char* {
        char* r = ws + off;
        off += (bytes + 255) & ~(size_t)255;
        return r;
    };
    int*     flag    = (int*)    alloc(4);
    int*     gcur    = (int*)    alloc(1024);
    int*     deg     = (int*)    alloc((size_t)N * 4);
    int*     offsets = (int*)    alloc((size_t)N * 4);
    float*   dis     = (float*)  alloc((size_t)N * 4);
    int*     pairs   = (int*)    alloc((size_t)nb * CAP * 4);   // 6.4 MB slack
    int*     csr     = (int*)    alloc((size_t)nb * CAP * 4);   // 6.4 MB slack
    ushort4* ybA     = (ushort4*)alloc((size_t)N * 64 * 2);     // fp16 rows
    ushort4* ybB     = (ushort4*)alloc((size_t)N * 64 * 2);

    // --- preprocessing: 3 kernels, ~50k global atomics total ---
    init_all<<<1, TPB, 0, stream>>>((const unsigned int*)ei, flag, gcur);
    p3_scatter<<<256, TPB, 0, stream>>>(ei, E, flag, gcur, pairs);
    p4_fill<<<nb, TPB, 0, stream>>>(pairs, gcur, deg, dis, offsets, csr, N);

    // --- fused layers ---
    const int gL = (N + 15) / 16;                        // 3125
    mm_first<<<gL, TPB, 0, stream>>>(x, W[0], dis, ybA, N);
    agg_mm<<<gL, TPB, 0, stream>>>(ybA, csr, offsets, deg, dis, bv[0], W[1], ybB, N);
    agg_mm<<<gL, TPB, 0, stream>>>(ybB, csr, offsets, deg, dis, bv[1], W[2], ybA, N);
    agg_final<<<gL, TPB, 0, stream>>>(ybA, csr, offsets, deg, dis, bv[2], Wl, bl,
                                      (float*)d_out, N);
}